// Round 8
// baseline (178.680 us; speedup 1.0000x reference)
//
#include <hip/hip_runtime.h>
#include <cmath>

#define CTXL 50
#define NC 300    // NCOND
#define NH 256    // NHID
#define NT 256    // threads per block
#define KPAD 320  // K padded to 10 k-steps of 32
#define ASTR 328  // fallback LDS A row stride in shorts

typedef float  f32x4 __attribute__((ext_vector_type(4)));
typedef short  s16x8 __attribute__((ext_vector_type(8)));
typedef short  s16x4 __attribute__((ext_vector_type(4)));

__device__ __forceinline__ ushort f2bf(float f) {
    unsigned u = __float_as_uint(f);
    unsigned r = (u + 0x7FFFu + ((u >> 16) & 1u)) >> 16;   // RNE
    return (ushort)r;
}
__device__ __forceinline__ float bf2f(ushort u) {
    return __uint_as_float(((unsigned)u) << 16);
}

// ---------------------------------------------------------------------------
// prepass: W1 [300][256] -> W1T bf16 [256][320]; W2 [256][300] -> W2T bf16 [300][256]
__global__ void convert_w(const float* __restrict__ W1, const float* __restrict__ W2,
                          ushort* __restrict__ W1T, ushort* __restrict__ W2T) {
    const int t  = threadIdx.x;
    const int bi = blockIdx.x;
    if (bi < KPAD) {
        W1T[(size_t)t * KPAD + bi] = (bi < NC) ? f2bf(W1[(size_t)bi * NH + t]) : (ushort)0;
    } else {
        const int j = bi - KPAD;           // < 300
        W2T[(size_t)j * NH + t] = f2bf(W2[(size_t)t * NC + j]);
    }
}

// ---------------------------------------------------------------------------
// K1: H[ntok][256] bf16 = relu(embs @ W1 + b1).
// Barrier-free, LDS-free. Swapped MFMA: D = mfma(W1frag, embfrag) gives
// D-col(l15)=emb-row, D-row(4*lhi+q)=W1-col -> lane holds 4 consecutive H
// cols of one H row -> direct ushort4 store, no transpose needed.
__global__ __launch_bounds__(NT, 2)
void k1_hidden(const float* __restrict__ embs,
               const float* __restrict__ b1,
               const ushort* __restrict__ W1T,
               ushort* __restrict__ H, int ntok) {
    const int m0   = blockIdx.x * 64;
    const int tid  = threadIdx.x;
    const int wave = tid >> 6;
    const int lane = tid & 63;
    const int l15  = lane & 15;
    const int lhi  = lane >> 4;

    int  erow[4];                     // emb row per row-tile (clamped for loads)
    bool rok[4];
    #pragma unroll
    for (int rt = 0; rt < 4; ++rt) {
        const int r = m0 + rt * 16 + l15;
        rok[rt]  = (r < ntok);
        erow[rt] = rok[rt] ? r : (ntok - 1);
    }
    const ushort* wbase = W1T + (size_t)(wave * 64 + l15) * KPAD + lhi * 8;

    f32x4 acc[4][4];                  // [ct][rt]
    #pragma unroll
    for (int ct = 0; ct < 4; ++ct)
        #pragma unroll
        for (int rt = 0; rt < 4; ++rt)
            acc[ct][rt] = (f32x4){0.f, 0.f, 0.f, 0.f};

    // main k-steps 0..8 (k = 0..287, all in-range)
    #pragma unroll
    for (int ks = 0; ks < 9; ++ks) {
        s16x8 wf[4];
        #pragma unroll
        for (int ct = 0; ct < 4; ++ct)
            wf[ct] = *(const s16x8*)(wbase + ct * 16 * KPAD + ks * 32);
        s16x8 ef[4];
        #pragma unroll
        for (int rt = 0; rt < 4; ++rt) {
            const float* src = embs + (size_t)erow[rt] * NC + ks * 32 + lhi * 8;
            const float4 a0 = *(const float4*)src;
            const float4 a1 = *(const float4*)(src + 4);
            s16x8 p;
            p[0] = (short)f2bf(a0.x); p[1] = (short)f2bf(a0.y);
            p[2] = (short)f2bf(a0.z); p[3] = (short)f2bf(a0.w);
            p[4] = (short)f2bf(a1.x); p[5] = (short)f2bf(a1.y);
            p[6] = (short)f2bf(a1.z); p[7] = (short)f2bf(a1.w);
            ef[rt] = p;
        }
        #pragma unroll
        for (int ct = 0; ct < 4; ++ct)
            #pragma unroll
            for (int rt = 0; rt < 4; ++rt)
                acc[ct][rt] = __builtin_amdgcn_mfma_f32_16x16x32_bf16(
                    wf[ct], ef[rt], acc[ct][rt], 0, 0, 0);
    }
    // k-step 9: k = 288..319; valid floats only 288..299
    {
        s16x8 wf[4];
        #pragma unroll
        for (int ct = 0; ct < 4; ++ct)
            wf[ct] = *(const s16x8*)(wbase + ct * 16 * KPAD + 9 * 32);
        s16x8 ef[4];
        #pragma unroll
        for (int rt = 0; rt < 4; ++rt) {
            s16x8 p = (s16x8){0, 0, 0, 0, 0, 0, 0, 0};
            const float* src = embs + (size_t)erow[rt] * NC + 288 + lhi * 8;
            if (lhi == 0) {
                const float4 a0 = *(const float4*)src;
                const float4 a1 = *(const float4*)(src + 4);
                p[0] = (short)f2bf(a0.x); p[1] = (short)f2bf(a0.y);
                p[2] = (short)f2bf(a0.z); p[3] = (short)f2bf(a0.w);
                p[4] = (short)f2bf(a1.x); p[5] = (short)f2bf(a1.y);
                p[6] = (short)f2bf(a1.z); p[7] = (short)f2bf(a1.w);
            } else if (lhi == 1) {
                const float4 a0 = *(const float4*)src;   // 296..299
                p[0] = (short)f2bf(a0.x); p[1] = (short)f2bf(a0.y);
                p[2] = (short)f2bf(a0.z); p[3] = (short)f2bf(a0.w);
            }
            ef[rt] = p;
        }
        #pragma unroll
        for (int ct = 0; ct < 4; ++ct)
            #pragma unroll
            for (int rt = 0; rt < 4; ++rt)
                acc[ct][rt] = __builtin_amdgcn_mfma_f32_16x16x32_bf16(
                    wf[ct], ef[rt], acc[ct][rt], 0, 0, 0);
    }

    // epilogue: relu(acc + b1) -> bf16, direct ushort4 stores (no transpose)
    #pragma unroll
    for (int ct = 0; ct < 4; ++ct) {
        const int col = wave * 64 + ct * 16 + 4 * lhi;
        const float4 b4 = *(const float4*)(b1 + col);
        #pragma unroll
        for (int rt = 0; rt < 4; ++rt) {
            if (rok[rt]) {
                ushort4 h;
                h.x = f2bf(fmaxf(acc[ct][rt][0] + b4.x, 0.0f));
                h.y = f2bf(fmaxf(acc[ct][rt][1] + b4.y, 0.0f));
                h.z = f2bf(fmaxf(acc[ct][rt][2] + b4.z, 0.0f));
                h.w = f2bf(fmaxf(acc[ct][rt][3] + b4.w, 0.0f));
                *(ushort4*)(H + (size_t)(m0 + rt * 16 + l15) * NH + col) = h;
            }
        }
    }
}

// ---------------------------------------------------------------------------
// K2: out[b] = sigmoid(mean_l H[ctx[b,l]] @ W2 + b2) * embs[x[b]]
// 2 samples per block (waves 0-1 -> s0, waves 2-3 -> s1).
// FIX vs round 7: pooled[] reduce now computes BOTH samples per thread
// (previous `if (tid < 2*NH)` never wrote pooled[1] since NT==256).
__global__ __launch_bounds__(NT, 4)
void k2_pool(const int* __restrict__ x,
             const int* __restrict__ ctx,
             const float* __restrict__ embs,
             const ushort* __restrict__ H,
             const ushort* __restrict__ W2T,
             const float* __restrict__ b2,
             float* __restrict__ out) {
    __shared__ int   ctxs[2 * CTXL];
    __shared__ float pool4[2][2][NH];
    __shared__ float pooled[2][NH];
    const int b0   = blockIdx.x * 2;
    const int tid  = threadIdx.x;
    const int wave = tid >> 6;
    const int lane = tid & 63;
    const int smp  = wave >> 1;       // sample 0/1
    const int half = wave & 1;        // row-half 0/1

    if (tid < 2 * CTXL) ctxs[tid] = ctx[b0 * CTXL + tid];   // contiguous
    __syncthreads();

    // each wave: 25 rows of its sample
    const int l0 = half * 25;
    float4 ps = make_float4(0.f, 0.f, 0.f, 0.f);
    #pragma unroll 5
    for (int i = 0; i < 25; ++i) {
        const int row = ctxs[smp * CTXL + l0 + i];
        const s16x4 h4 = *(const s16x4*)(H + (size_t)row * NH + lane * 4);
        ps.x += bf2f((ushort)h4[0]);
        ps.y += bf2f((ushort)h4[1]);
        ps.z += bf2f((ushort)h4[2]);
        ps.w += bf2f((ushort)h4[3]);
    }
    *(float4*)(&pool4[smp][half][lane * 4]) = ps;
    __syncthreads();

    // FIXED reduce: every thread (tid = column) handles both samples
    pooled[0][tid] = (pool4[0][0][tid] + pool4[0][1][tid]) * (1.0f / CTXL);
    pooled[1][tid] = (pool4[1][0][tid] + pool4[1][1][tid]) * (1.0f / CTXL);
    __syncthreads();

    const int x0 = x[b0], x1 = x[b0 + 1];
    for (int j = tid; j < NC; j += NT) {
        float s0 = b2[j], s1 = s0;
        const s16x8* wrow = (const s16x8*)(W2T + (size_t)j * NH);
        #pragma unroll 8
        for (int c = 0; c < NH / 8; ++c) {
            const s16x8 w8 = wrow[c];
            #pragma unroll
            for (int q = 0; q < 8; ++q) {
                const float wv = bf2f((ushort)w8[q]);
                s0 = fmaf(pooled[0][c * 8 + q], wv, s0);
                s1 = fmaf(pooled[1][c * 8 + q], wv, s1);
            }
        }
        out[(size_t)b0 * NC + j] =
            (1.0f / (1.0f + __expf(-s0))) * embs[(size_t)x0 * NC + j];
        out[(size_t)(b0 + 1) * NC + j] =
            (1.0f / (1.0f + __expf(-s1))) * embs[(size_t)x1 * NC + j];
    }
}

// ---------------------------------------------------------------------------
// fallback (round-2-proven structure): fused per-sample kernel, fp32 gather
__global__ __launch_bounds__(NT, 4)
void esa_fallback(const int* __restrict__ x, const int* __restrict__ ctx,
                  const float* __restrict__ embs, const float* __restrict__ b1,
                  const float* __restrict__ b2, const ushort* __restrict__ W1T,
                  const ushort* __restrict__ W2T, float* __restrict__ out) {
    __shared__ short A[CTXL * ASTR];
    __shared__ float xemb[NC];
    __shared__ float pooled[NH];
    const int b = blockIdx.x, tid = threadIdx.x;
    const int wave = tid >> 6, lane = tid & 63, l15 = lane & 15, lhi = lane >> 4;

    const int r = tid >> 2, cq = tid & 3;
    if (r < CTXL) {
        const int row = ctx[b * CTXL + r];
        const float* src = embs + (size_t)row * NC;
        #pragma unroll
        for (int i = 0; i < 19; ++i) {
            const int c = cq + 4 * i;
            if (c < 75) {
                const float4 v = *(const float4*)(src + c * 4);
                uint2 p;
                p.x = (unsigned)f2bf(v.x) | ((unsigned)f2bf(v.y) << 16);
                p.y = (unsigned)f2bf(v.z) | ((unsigned)f2bf(v.w) << 16);
                *(uint2*)((char*)A + (size_t)r * (ASTR * 2) + c * 8) = p;
            }
        }
        #pragma unroll
        for (int k = cq; k < 5; k += 4)
            *(uint2*)((char*)A + (size_t)r * (ASTR * 2) + 600 + k * 8) = make_uint2(0u, 0u);
    }
    { const int row = x[b];
      if (tid < NC / 4) ((float4*)xemb)[tid] = ((const float4*)(embs + (size_t)row * NC))[tid]; }
    __syncthreads();

    f32x4 acc[4][4];
    #pragma unroll
    for (int mt = 0; mt < 4; ++mt)
        #pragma unroll
        for (int nt = 0; nt < 4; ++nt) acc[mt][nt] = (f32x4){0.f, 0.f, 0.f, 0.f};
    int abyte[4];
    #pragma unroll
    for (int mt = 0; mt < 4; ++mt) {
        int rr = mt * 16 + l15; if (rr >= CTXL) rr = 0;
        abyte[mt] = rr * (ASTR * 2) + lhi * 16;
    }
    const ushort* wb = W1T + (size_t)(wave * 64 + l15) * KPAD + lhi * 8;
    #pragma unroll
    for (int ks = 0; ks < KPAD / 32; ++ks) {
        s16x8 af[4], bfr[4];
        #pragma unroll
        for (int mt = 0; mt < 4; ++mt)
            af[mt] = *(const s16x8*)((const char*)A + abyte[mt] + ks * 64);
        #pragma unroll
        for (int nt = 0; nt < 4; ++nt)
            bfr[nt] = *(const s16x8*)(wb + nt * 16 * KPAD + ks * 32);
        #pragma unroll
        for (int mt = 0; mt < 4; ++mt)
            #pragma unroll
            for (int nt = 0; nt < 4; ++nt)
                acc[mt][nt] = __builtin_amdgcn_mfma_f32_16x16x32_bf16(
                    af[mt], bfr[nt], acc[mt][nt], 0, 0, 0);
    }
    #pragma unroll
    for (int nt = 0; nt < 4; ++nt) {
        const float bb = b1[wave * 64 + nt * 16 + l15];
        float s = 0.0f;
        #pragma unroll
        for (int mt = 0; mt < 4; ++mt)
            #pragma unroll
            for (int q = 0; q < 4; ++q) {
                const int row = mt * 16 + lhi * 4 + q;
                const float v = fmaxf(acc[mt][nt][q] + bb, 0.0f);
                s += (row < CTXL) ? v : 0.0f;
            }
        s += __shfl_xor(s, 16);
        s += __shfl_xor(s, 32);
        if (lhi == 0) pooled[wave * 64 + nt * 16 + l15] = s * (1.0f / CTXL);
    }
    __syncthreads();
    for (int j = tid; j < NC; j += NT) {
        float s = b2[j];
        const s16x8* wrow = (const s16x8*)(W2T + (size_t)j * NH);
        #pragma unroll 8
        for (int c = 0; c < NH / 8; ++c) {
            const s16x8 w8 = wrow[c];
            const float4 p0 = *(const float4*)(&pooled[c * 8]);
            const float4 p1 = *(const float4*)(&pooled[c * 8 + 4]);
            s = fmaf(p0.x, bf2f((ushort)w8[0]), s);
            s = fmaf(p0.y, bf2f((ushort)w8[1]), s);
            s = fmaf(p0.z, bf2f((ushort)w8[2]), s);
            s = fmaf(p0.w, bf2f((ushort)w8[3]), s);
            s = fmaf(p1.x, bf2f((ushort)w8[4]), s);
            s = fmaf(p1.y, bf2f((ushort)w8[5]), s);
            s = fmaf(p1.z, bf2f((ushort)w8[6]), s);
            s = fmaf(p1.w, bf2f((ushort)w8[7]), s);
        }
        const float g = 1.0f / (1.0f + __expf(-s));
        out[(size_t)b * NC + j] = g * xemb[j];
    }
}

extern "C" void kernel_launch(void* const* d_in, const int* in_sizes, int n_in,
                              void* d_out, int out_size, void* d_ws, size_t ws_size,
                              hipStream_t stream) {
    const int*   x    = (const int*)d_in[0];
    const int*   ctx  = (const int*)d_in[1];
    const float* embs = (const float*)d_in[2];
    const float* W1   = (const float*)d_in[3];
    const float* b1   = (const float*)d_in[4];
    const float* W2   = (const float*)d_in[5];
    const float* b2   = (const float*)d_in[6];
    float* out = (float*)d_out;

    const int B    = in_sizes[0];
    const int ntok = in_sizes[2] / NC;

    const size_t h_bytes   = (size_t)ntok * NH * 2;   // 51.2 MB
    const size_t w1t_bytes = (size_t)NH * KPAD * 2;   // 160 KB
    const size_t w2t_bytes = (size_t)NC * NH * 2;     // 150 KB

    if (ws_size >= h_bytes + w1t_bytes + w2t_bytes && (B & 1) == 0) {
        ushort* H   = (ushort*)d_ws;
        ushort* W1T = (ushort*)((char*)d_ws + h_bytes);
        ushort* W2T = (ushort*)((char*)d_ws + h_bytes + w1t_bytes);
        convert_w<<<KPAD + NC, NT, 0, stream>>>(W1, W2, W1T, W2T);
        k1_hidden<<<(ntok + 63) / 64, NT, 0, stream>>>(embs, b1, W1T, H, ntok);
        k2_pool<<<B / 2, NT, 0, stream>>>(x, ctx, embs, H, W2T, b2, out);
    } else {
        ushort* W1T = (ushort*)d_ws;
        ushort* W2T = (ushort*)((char*)d_ws + w1t_bytes);
        convert_w<<<KPAD + NC, NT, 0, stream>>>(W1, W2, W1T, W2T);
        esa_fallback<<<B, NT, 0, stream>>>(x, ctx, embs, b1, b2, W1T, W2T, out);
    }
}

// Round 9
// 161.375 us; speedup vs baseline: 1.1072x; 1.1072x over previous
//
#include <hip/hip_runtime.h>
#include <cmath>

#define CTXL 50
#define NC 300    // NCOND
#define NH 256    // NHID
#define NT 256    // threads per block
#define KPAD 320  // K padded to 10 k-steps of 32
#define ASTR 328  // LDS A row stride in shorts (656 B; 164 dwords = 4 mod 32)
#define MR 32     // K1 rows per block (LDS 21 KB -> ~7 blocks/CU)

typedef float  f32x4 __attribute__((ext_vector_type(4)));
typedef short  s16x8 __attribute__((ext_vector_type(8)));
typedef short  s16x4 __attribute__((ext_vector_type(4)));

__device__ __forceinline__ ushort f2bf(float f) {
    unsigned u = __float_as_uint(f);
    unsigned r = (u + 0x7FFFu + ((u >> 16) & 1u)) >> 16;   // RNE
    return (ushort)r;
}
__device__ __forceinline__ float bf2f(ushort u) {
    return __uint_as_float(((unsigned)u) << 16);
}

// ---------------------------------------------------------------------------
// prepass: W1 [300][256] -> W1T bf16 [256][320]; W2 [256][300] -> W2T bf16 [300][256]
__global__ void convert_w(const float* __restrict__ W1, const float* __restrict__ W2,
                          ushort* __restrict__ W1T, ushort* __restrict__ W2T) {
    const int t  = threadIdx.x;
    const int bi = blockIdx.x;
    if (bi < KPAD) {
        W1T[(size_t)t * KPAD + bi] = (bi < NC) ? f2bf(W1[(size_t)bi * NH + t]) : (ushort)0;
    } else {
        const int j = bi - KPAD;           // < 300
        W2T[(size_t)j * NH + t] = f2bf(W2[(size_t)t * NC + j]);
    }
}

// ---------------------------------------------------------------------------
// K1 v3: H[ntok][256] bf16 = relu(embs @ W1 + b1).
// Cooperative LDS staging (tile loaded ONCE per block, coalesced) + swapped
// MFMA (D = mfma(W1frag, embfrag): D-col=emb row, D-row=W1 col -> lane holds
// 4 consecutive H cols of one row -> direct ushort4 store). One barrier.
// MR=32 rows/block -> 21 KB LDS -> ~7 blocks/CU for latency hiding.
__global__ __launch_bounds__(NT, 2)
void k1_hidden(const float* __restrict__ embs,
               const float* __restrict__ b1,
               const ushort* __restrict__ W1T,
               ushort* __restrict__ H, int ntok) {
    __shared__ short A[MR * ASTR];        // 20992 B
    const int m0   = blockIdx.x * MR;
    const int tid  = threadIdx.x;
    const int wave = tid >> 6;
    const int lane = tid & 63;
    const int l15  = lane & 15;
    const int lhi  = lane >> 4;

    // ---- stage MR rows fp32 -> bf16 LDS (coalesced, chunk-major, 5 iters) --
    #pragma unroll
    for (int i = 0; i < MR * 40 / NT; ++i) {
        const int g = tid + NT * i;
        const int r = g / 40;
        const int c = g - r * 40;                    // 16B chunk 0..39
        int row = m0 + r; if (row >= ntok) row = ntok - 1;
        const float* src = embs + (size_t)row * NC + c * 8;
        float v[8];
        if (c < 37) {
            const float4 a0 = *(const float4*)src;
            const float4 a1 = *(const float4*)(src + 4);
            v[0]=a0.x; v[1]=a0.y; v[2]=a0.z; v[3]=a0.w;
            v[4]=a1.x; v[5]=a1.y; v[6]=a1.z; v[7]=a1.w;
        } else if (c == 37) {
            const float4 a0 = *(const float4*)src;
            v[0]=a0.x; v[1]=a0.y; v[2]=a0.z; v[3]=a0.w;
            v[4]=v[5]=v[6]=v[7]=0.0f;
        } else {
            #pragma unroll
            for (int q = 0; q < 8; ++q) v[q] = 0.0f;
        }
        s16x8 p;
        #pragma unroll
        for (int q = 0; q < 8; ++q) p[q] = (short)f2bf(v[q]);
        *(s16x8*)((char*)A + (size_t)r * (ASTR * 2) + c * 16) = p;
    }
    __syncthreads();

    // ---- MFMA: acc[ct][rt] = W1(cols) x emb(rows) over K ------------------
    const ushort* wbase = W1T + (size_t)(wave * 64 + l15) * KPAD + lhi * 8;

    f32x4 acc[4][2];
    #pragma unroll
    for (int ct = 0; ct < 4; ++ct)
        #pragma unroll
        for (int rt = 0; rt < 2; ++rt)
            acc[ct][rt] = (f32x4){0.f, 0.f, 0.f, 0.f};

    #pragma unroll
    for (int ks = 0; ks < KPAD / 32; ++ks) {
        s16x8 wf[4], ef[2];
        #pragma unroll
        for (int ct = 0; ct < 4; ++ct)
            wf[ct] = *(const s16x8*)(wbase + ct * 16 * KPAD + ks * 32);
        #pragma unroll
        for (int rt = 0; rt < 2; ++rt)
            ef[rt] = *(const s16x8*)((const char*)A +
                        (size_t)(rt * 16 + l15) * (ASTR * 2) + ks * 64 + lhi * 16);
        #pragma unroll
        for (int ct = 0; ct < 4; ++ct)
            #pragma unroll
            for (int rt = 0; rt < 2; ++rt)
                acc[ct][rt] = __builtin_amdgcn_mfma_f32_16x16x32_bf16(
                    wf[ct], ef[rt], acc[ct][rt], 0, 0, 0);
    }

    // ---- epilogue: relu(acc + b1) -> bf16, direct ushort4 stores ----------
    #pragma unroll
    for (int ct = 0; ct < 4; ++ct) {
        const int col = wave * 64 + ct * 16 + 4 * lhi;
        const float4 b4 = *(const float4*)(b1 + col);
        #pragma unroll
        for (int rt = 0; rt < 2; ++rt) {
            const int row = m0 + rt * 16 + l15;
            if (row < ntok) {
                ushort4 h;
                h.x = f2bf(fmaxf(acc[ct][rt][0] + b4.x, 0.0f));
                h.y = f2bf(fmaxf(acc[ct][rt][1] + b4.y, 0.0f));
                h.z = f2bf(fmaxf(acc[ct][rt][2] + b4.z, 0.0f));
                h.w = f2bf(fmaxf(acc[ct][rt][3] + b4.w, 0.0f));
                *(ushort4*)(H + (size_t)row * NH + col) = h;
            }
        }
    }
}

// ---------------------------------------------------------------------------
// K2: out[b] = sigmoid(mean_l H[ctx[b,l]] @ W2 + b2) * embs[x[b]]
// 2 samples per block (waves 0-1 -> s0, waves 2-3 -> s1).
__global__ __launch_bounds__(NT, 4)
void k2_pool(const int* __restrict__ x,
             const int* __restrict__ ctx,
             const float* __restrict__ embs,
             const ushort* __restrict__ H,
             const ushort* __restrict__ W2T,
             const float* __restrict__ b2,
             float* __restrict__ out) {
    __shared__ int   ctxs[2 * CTXL];
    __shared__ float pool4[2][2][NH];
    __shared__ float pooled[2][NH];
    const int b0   = blockIdx.x * 2;
    const int tid  = threadIdx.x;
    const int wave = tid >> 6;
    const int lane = tid & 63;
    const int smp  = wave >> 1;       // sample 0/1
    const int half = wave & 1;        // row-half 0/1

    if (tid < 2 * CTXL) ctxs[tid] = ctx[b0 * CTXL + tid];   // contiguous
    __syncthreads();

    const int l0 = half * 25;
    float4 ps = make_float4(0.f, 0.f, 0.f, 0.f);
    #pragma unroll 5
    for (int i = 0; i < 25; ++i) {
        const int row = ctxs[smp * CTXL + l0 + i];
        const s16x4 h4 = *(const s16x4*)(H + (size_t)row * NH + lane * 4);
        ps.x += bf2f((ushort)h4[0]);
        ps.y += bf2f((ushort)h4[1]);
        ps.z += bf2f((ushort)h4[2]);
        ps.w += bf2f((ushort)h4[3]);
    }
    *(float4*)(&pool4[smp][half][lane * 4]) = ps;
    __syncthreads();

    pooled[0][tid] = (pool4[0][0][tid] + pool4[0][1][tid]) * (1.0f / CTXL);
    pooled[1][tid] = (pool4[1][0][tid] + pool4[1][1][tid]) * (1.0f / CTXL);
    __syncthreads();

    const int x0 = x[b0], x1 = x[b0 + 1];
    for (int j = tid; j < NC; j += NT) {
        float s0 = b2[j], s1 = s0;
        const s16x8* wrow = (const s16x8*)(W2T + (size_t)j * NH);
        #pragma unroll 8
        for (int c = 0; c < NH / 8; ++c) {
            const s16x8 w8 = wrow[c];
            #pragma unroll
            for (int q = 0; q < 8; ++q) {
                const float wv = bf2f((ushort)w8[q]);
                s0 = fmaf(pooled[0][c * 8 + q], wv, s0);
                s1 = fmaf(pooled[1][c * 8 + q], wv, s1);
            }
        }
        out[(size_t)b0 * NC + j] =
            (1.0f / (1.0f + __expf(-s0))) * embs[(size_t)x0 * NC + j];
        out[(size_t)(b0 + 1) * NC + j] =
            (1.0f / (1.0f + __expf(-s1))) * embs[(size_t)x1 * NC + j];
    }
}

// ---------------------------------------------------------------------------
// fallback (round-2-proven structure): fused per-sample kernel, fp32 gather
__global__ __launch_bounds__(NT, 4)
void esa_fallback(const int* __restrict__ x, const int* __restrict__ ctx,
                  const float* __restrict__ embs, const float* __restrict__ b1,
                  const float* __restrict__ b2, const ushort* __restrict__ W1T,
                  const ushort* __restrict__ W2T, float* __restrict__ out) {
    __shared__ short A[CTXL * ASTR];
    __shared__ float xemb[NC];
    __shared__ float pooled[NH];
    const int b = blockIdx.x, tid = threadIdx.x;
    const int wave = tid >> 6, lane = tid & 63, l15 = lane & 15, lhi = lane >> 4;

    const int r = tid >> 2, cq = tid & 3;
    if (r < CTXL) {
        const int row = ctx[b * CTXL + r];
        const float* src = embs + (size_t)row * NC;
        #pragma unroll
        for (int i = 0; i < 19; ++i) {
            const int c = cq + 4 * i;
            if (c < 75) {
                const float4 v = *(const float4*)(src + c * 4);
                uint2 p;
                p.x = (unsigned)f2bf(v.x) | ((unsigned)f2bf(v.y) << 16);
                p.y = (unsigned)f2bf(v.z) | ((unsigned)f2bf(v.w) << 16);
                *(uint2*)((char*)A + (size_t)r * (ASTR * 2) + c * 8) = p;
            }
        }
        #pragma unroll
        for (int k = cq; k < 5; k += 4)
            *(uint2*)((char*)A + (size_t)r * (ASTR * 2) + 600 + k * 8) = make_uint2(0u, 0u);
    }
    { const int row = x[b];
      if (tid < NC / 4) ((float4*)xemb)[tid] = ((const float4*)(embs + (size_t)row * NC))[tid]; }
    __syncthreads();

    f32x4 acc[4][4];
    #pragma unroll
    for (int mt = 0; mt < 4; ++mt)
        #pragma unroll
        for (int nt = 0; nt < 4; ++nt) acc[mt][nt] = (f32x4){0.f, 0.f, 0.f, 0.f};
    int abyte[4];
    #pragma unroll
    for (int mt = 0; mt < 4; ++mt) {
        int rr = mt * 16 + l15; if (rr >= CTXL) rr = 0;
        abyte[mt] = rr * (ASTR * 2) + lhi * 16;
    }
    const ushort* wb = W1T + (size_t)(wave * 64 + l15) * KPAD + lhi * 8;
    #pragma unroll
    for (int ks = 0; ks < KPAD / 32; ++ks) {
        s16x8 af[4], bfr[4];
        #pragma unroll
        for (int mt = 0; mt < 4; ++mt)
            af[mt] = *(const s16x8*)((const char*)A + abyte[mt] + ks * 64);
        #pragma unroll
        for (int nt = 0; nt < 4; ++nt)
            bfr[nt] = *(const s16x8*)(wb + nt * 16 * KPAD + ks * 32);
        #pragma unroll
        for (int mt = 0; mt < 4; ++mt)
            #pragma unroll
            for (int nt = 0; nt < 4; ++nt)
                acc[mt][nt] = __builtin_amdgcn_mfma_f32_16x16x32_bf16(
                    af[mt], bfr[nt], acc[mt][nt], 0, 0, 0);
    }
    #pragma unroll
    for (int nt = 0; nt < 4; ++nt) {
        const float bb = b1[wave * 64 + nt * 16 + l15];
        float s = 0.0f;
        #pragma unroll
        for (int mt = 0; mt < 4; ++mt)
            #pragma unroll
            for (int q = 0; q < 4; ++q) {
                const int row = mt * 16 + lhi * 4 + q;
                const float v = fmaxf(acc[mt][nt][q] + bb, 0.0f);
                s += (row < CTXL) ? v : 0.0f;
            }
        s += __shfl_xor(s, 16);
        s += __shfl_xor(s, 32);
        if (lhi == 0) pooled[wave * 64 + nt * 16 + l15] = s * (1.0f / CTXL);
    }
    __syncthreads();
    for (int j = tid; j < NC; j += NT) {
        float s = b2[j];
        const s16x8* wrow = (const s16x8*)(W2T + (size_t)j * NH);
        #pragma unroll 8
        for (int c = 0; c < NH / 8; ++c) {
            const s16x8 w8 = wrow[c];
            const float4 p0 = *(const float4*)(&pooled[c * 8]);
            const float4 p1 = *(const float4*)(&pooled[c * 8 + 4]);
            s = fmaf(p0.x, bf2f((ushort)w8[0]), s);
            s = fmaf(p0.y, bf2f((ushort)w8[1]), s);
            s = fmaf(p0.z, bf2f((ushort)w8[2]), s);
            s = fmaf(p0.w, bf2f((ushort)w8[3]), s);
            s = fmaf(p1.x, bf2f((ushort)w8[4]), s);
            s = fmaf(p1.y, bf2f((ushort)w8[5]), s);
            s = fmaf(p1.z, bf2f((ushort)w8[6]), s);
            s = fmaf(p1.w, bf2f((ushort)w8[7]), s);
        }
        const float g = 1.0f / (1.0f + __expf(-s));
        out[(size_t)b * NC + j] = g * xemb[j];
    }
}

extern "C" void kernel_launch(void* const* d_in, const int* in_sizes, int n_in,
                              void* d_out, int out_size, void* d_ws, size_t ws_size,
                              hipStream_t stream) {
    const int*   x    = (const int*)d_in[0];
    const int*   ctx  = (const int*)d_in[1];
    const float* embs = (const float*)d_in[2];
    const float* W1   = (const float*)d_in[3];
    const float* b1   = (const float*)d_in[4];
    const float* W2   = (const float*)d_in[5];
    const float* b2   = (const float*)d_in[6];
    float* out = (float*)d_out;

    const int B    = in_sizes[0];
    const int ntok = in_sizes[2] / NC;

    const size_t h_bytes   = (size_t)ntok * NH * 2;   // 51.2 MB
    const size_t w1t_bytes = (size_t)NH * KPAD * 2;   // 160 KB
    const size_t w2t_bytes = (size_t)NC * NH * 2;     // 150 KB

    if (ws_size >= h_bytes + w1t_bytes + w2t_bytes && (B & 1) == 0) {
        ushort* H   = (ushort*)d_ws;
        ushort* W1T = (ushort*)((char*)d_ws + h_bytes);
        ushort* W2T = (ushort*)((char*)d_ws + h_bytes + w1t_bytes);
        convert_w<<<KPAD + NC, NT, 0, stream>>>(W1, W2, W1T, W2T);
        k1_hidden<<<(ntok + MR - 1) / MR, NT, 0, stream>>>(embs, b1, W1T, H, ntok);
        k2_pool<<<B / 2, NT, 0, stream>>>(x, ctx, embs, H, W2T, b2, out);
    } else {
        ushort* W1T = (ushort*)d_ws;
        ushort* W2T = (ushort*)((char*)d_ws + w1t_bytes);
        convert_w<<<KPAD + NC, NT, 0, stream>>>(W1, W2, W1T, W2T);
        esa_fallback<<<B, NT, 0, stream>>>(x, ctx, embs, b1, b2, W1T, W2T, out);
    }
}

// Round 10
// 104.094 us; speedup vs baseline: 1.7165x; 1.5503x over previous
//
#include <hip/hip_runtime.h>
#include <cmath>

#define CTXL 50
#define NC 300    // NCOND
#define NH 256    // NHID
#define NT 256    // threads per block
#define KPAD 320  // K padded to 10 k-steps of 32
#define ASTR 328  // LDS A row stride in shorts (656 B)
#define MR 32     // K1 rows per tile
#define NKS 10    // k-steps

typedef float  f32x4 __attribute__((ext_vector_type(4)));
typedef short  s16x8 __attribute__((ext_vector_type(8)));
typedef short  s16x4 __attribute__((ext_vector_type(4)));

__device__ __forceinline__ ushort f2bf(float f) {
    unsigned u = __float_as_uint(f);
    unsigned r = (u + 0x7FFFu + ((u >> 16) & 1u)) >> 16;   // RNE
    return (ushort)r;
}
__device__ __forceinline__ float bf2f(ushort u) {
    return __uint_as_float(((unsigned)u) << 16);
}

// ---------------------------------------------------------------------------
// prepass: W1 [300][256] -> W1T bf16 [256][320]; W2 [256][300] -> W2T bf16 [300][256]
__global__ void convert_w(const float* __restrict__ W1, const float* __restrict__ W2,
                          ushort* __restrict__ W1T, ushort* __restrict__ W2T) {
    const int t  = threadIdx.x;
    const int bi = blockIdx.x;
    if (bi < KPAD) {
        W1T[(size_t)t * KPAD + bi] = (bi < NC) ? f2bf(W1[(size_t)bi * NH + t]) : (ushort)0;
    } else {
        const int j = bi - KPAD;           // < 300
        W2T[(size_t)j * NH + t] = f2bf(W2[(size_t)t * NC + j]);
    }
}

// ---------------------------------------------------------------------------
// K1 v4: H[ntok][256] bf16 = relu(embs @ W1 + b1).
// W1T slice held in REGISTERS (40 x s16x8 = 160 VGPR, static idx), loaded once
// per block; grid-stride over M-tiles amortizes it ~6x. Per tile: cooperative
// LDS stage + 10x(2 ds_read + 8 MFMA from regs) + swapped-layout direct store.
// 512 blocks = exactly 2/CU resident at 2 waves/SIMD (256-VGPR cap).
__global__ __launch_bounds__(NT, 2)
void k1_hidden(const float* __restrict__ embs,
               const float* __restrict__ b1,
               const ushort* __restrict__ W1T,
               ushort* __restrict__ H, int ntok, int ntiles) {
    __shared__ short A[MR * ASTR];        // 20992 B
    const int tid  = threadIdx.x;
    const int wave = tid >> 6;
    const int lane = tid & 63;
    const int l15  = lane & 15;
    const int lhi  = lane >> 4;

    // ---- preload W1T fragments for this wave's 64 cols (once per block) ----
    const ushort* wbase = W1T + (size_t)(wave * 64 + l15) * KPAD + lhi * 8;
    s16x8 wf[4][NKS];
    #pragma unroll
    for (int ct = 0; ct < 4; ++ct)
        #pragma unroll
        for (int ks = 0; ks < NKS; ++ks)
            wf[ct][ks] = *(const s16x8*)(wbase + ct * 16 * KPAD + ks * 32);

    // bias fragment for epilogue (per ct, 4 consecutive cols at 4*lhi)
    f32x4 bfrag[4];
    #pragma unroll
    for (int ct = 0; ct < 4; ++ct)
        bfrag[ct] = *(const f32x4*)(b1 + wave * 64 + ct * 16 + 4 * lhi);

    for (int t = blockIdx.x; t < ntiles; t += gridDim.x) {
        const int m0 = t * MR;

        // ---- stage MR rows fp32 -> bf16 LDS (coalesced, 5 iters) ----------
        #pragma unroll
        for (int i = 0; i < MR * 40 / NT; ++i) {
            const int g = tid + NT * i;
            const int r = g / 40;
            const int c = g - r * 40;                // 16B chunk 0..39
            int row = m0 + r; if (row >= ntok) row = ntok - 1;
            const float* src = embs + (size_t)row * NC + c * 8;
            float v[8];
            if (c < 37) {
                const float4 a0 = *(const float4*)src;
                const float4 a1 = *(const float4*)(src + 4);
                v[0]=a0.x; v[1]=a0.y; v[2]=a0.z; v[3]=a0.w;
                v[4]=a1.x; v[5]=a1.y; v[6]=a1.z; v[7]=a1.w;
            } else if (c == 37) {
                const float4 a0 = *(const float4*)src;
                v[0]=a0.x; v[1]=a0.y; v[2]=a0.z; v[3]=a0.w;
                v[4]=v[5]=v[6]=v[7]=0.0f;
            } else {
                #pragma unroll
                for (int q = 0; q < 8; ++q) v[q] = 0.0f;
            }
            s16x8 p;
            #pragma unroll
            for (int q = 0; q < 8; ++q) p[q] = (short)f2bf(v[q]);
            *(s16x8*)((char*)A + (size_t)r * (ASTR * 2) + c * 16) = p;
        }
        __syncthreads();

        // ---- MFMA from registers + LDS ------------------------------------
        f32x4 acc[4][2];
        #pragma unroll
        for (int ct = 0; ct < 4; ++ct)
            #pragma unroll
            for (int rt = 0; rt < 2; ++rt)
                acc[ct][rt] = (f32x4){0.f, 0.f, 0.f, 0.f};

        #pragma unroll
        for (int ks = 0; ks < NKS; ++ks) {
            s16x8 ef[2];
            #pragma unroll
            for (int rt = 0; rt < 2; ++rt)
                ef[rt] = *(const s16x8*)((const char*)A +
                            (size_t)(rt * 16 + l15) * (ASTR * 2) + ks * 64 + lhi * 16);
            #pragma unroll
            for (int ct = 0; ct < 4; ++ct)
                #pragma unroll
                for (int rt = 0; rt < 2; ++rt)
                    acc[ct][rt] = __builtin_amdgcn_mfma_f32_16x16x32_bf16(
                        wf[ct][ks], ef[rt], acc[ct][rt], 0, 0, 0);
        }

        // ---- epilogue: relu(acc + b1) -> bf16, direct ushort4 stores ------
        #pragma unroll
        for (int ct = 0; ct < 4; ++ct) {
            const int col = wave * 64 + ct * 16 + 4 * lhi;
            #pragma unroll
            for (int rt = 0; rt < 2; ++rt) {
                const int row = m0 + rt * 16 + l15;
                if (row < ntok) {
                    ushort4 h;
                    h.x = f2bf(fmaxf(acc[ct][rt][0] + bfrag[ct][0], 0.0f));
                    h.y = f2bf(fmaxf(acc[ct][rt][1] + bfrag[ct][1], 0.0f));
                    h.z = f2bf(fmaxf(acc[ct][rt][2] + bfrag[ct][2], 0.0f));
                    h.w = f2bf(fmaxf(acc[ct][rt][3] + bfrag[ct][3], 0.0f));
                    *(ushort4*)(H + (size_t)row * NH + col) = h;
                }
            }
        }
        __syncthreads();     // A reads done before next tile's stage
    }
}

// ---------------------------------------------------------------------------
// K2: out[b] = sigmoid(mean_l H[ctx[b,l]] @ W2 + b2) * embs[x[b]]
// 4 samples per block: wave w pools its sample's 50 rows; the W2T row stream
// (150 KB/block) is shared by 4 gates -> half the L2 traffic of 2-sample.
__global__ __launch_bounds__(NT, 4)
void k2_pool(const int* __restrict__ x,
             const int* __restrict__ ctx,
             const float* __restrict__ embs,
             const ushort* __restrict__ H,
             const ushort* __restrict__ W2T,
             const float* __restrict__ b2,
             float* __restrict__ out) {
    __shared__ int   ctxs[4 * CTXL];
    __shared__ float pooled[4][NH];
    const int b0   = blockIdx.x * 4;
    const int tid  = threadIdx.x;
    const int wave = tid >> 6;
    const int lane = tid & 63;

    if (tid < 4 * CTXL) ctxs[tid] = ctx[b0 * CTXL + tid];   // contiguous
    __syncthreads();

    {
        float4 ps = make_float4(0.f, 0.f, 0.f, 0.f);
        #pragma unroll 10
        for (int i = 0; i < CTXL; ++i) {
            const int row = ctxs[wave * CTXL + i];
            const s16x4 h4 = *(const s16x4*)(H + (size_t)row * NH + lane * 4);
            ps.x += bf2f((ushort)h4[0]);
            ps.y += bf2f((ushort)h4[1]);
            ps.z += bf2f((ushort)h4[2]);
            ps.w += bf2f((ushort)h4[3]);
        }
        ps.x *= (1.0f / CTXL); ps.y *= (1.0f / CTXL);
        ps.z *= (1.0f / CTXL); ps.w *= (1.0f / CTXL);
        *(float4*)(&pooled[wave][lane * 4]) = ps;
    }
    __syncthreads();

    const int x0 = x[b0], x1 = x[b0 + 1], x2 = x[b0 + 2], x3 = x[b0 + 3];
    for (int j = tid; j < NC; j += NT) {
        float s0 = b2[j], s1 = s0, s2 = s0, s3 = s0;
        const s16x8* wrow = (const s16x8*)(W2T + (size_t)j * NH);
        #pragma unroll 8
        for (int c = 0; c < NH / 8; ++c) {
            const s16x8 w8 = wrow[c];
            #pragma unroll
            for (int q = 0; q < 8; ++q) {
                const float wv = bf2f((ushort)w8[q]);
                s0 = fmaf(pooled[0][c * 8 + q], wv, s0);
                s1 = fmaf(pooled[1][c * 8 + q], wv, s1);
                s2 = fmaf(pooled[2][c * 8 + q], wv, s2);
                s3 = fmaf(pooled[3][c * 8 + q], wv, s3);
            }
        }
        out[(size_t)(b0 + 0) * NC + j] =
            (1.0f / (1.0f + __expf(-s0))) * embs[(size_t)x0 * NC + j];
        out[(size_t)(b0 + 1) * NC + j] =
            (1.0f / (1.0f + __expf(-s1))) * embs[(size_t)x1 * NC + j];
        out[(size_t)(b0 + 2) * NC + j] =
            (1.0f / (1.0f + __expf(-s2))) * embs[(size_t)x2 * NC + j];
        out[(size_t)(b0 + 3) * NC + j] =
            (1.0f / (1.0f + __expf(-s3))) * embs[(size_t)x3 * NC + j];
    }
}

// ---------------------------------------------------------------------------
// fallback (round-2-proven structure): fused per-sample kernel, fp32 gather
__global__ __launch_bounds__(NT, 4)
void esa_fallback(const int* __restrict__ x, const int* __restrict__ ctx,
                  const float* __restrict__ embs, const float* __restrict__ b1,
                  const float* __restrict__ b2, const ushort* __restrict__ W1T,
                  const ushort* __restrict__ W2T, float* __restrict__ out) {
    __shared__ short A[CTXL * ASTR];
    __shared__ float xemb[NC];
    __shared__ float pooled[NH];
    const int b = blockIdx.x, tid = threadIdx.x;
    const int wave = tid >> 6, lane = tid & 63, l15 = lane & 15, lhi = lane >> 4;

    const int r = tid >> 2, cq = tid & 3;
    if (r < CTXL) {
        const int row = ctx[b * CTXL + r];
        const float* src = embs + (size_t)row * NC;
        #pragma unroll
        for (int i = 0; i < 19; ++i) {
            const int c = cq + 4 * i;
            if (c < 75) {
                const float4 v = *(const float4*)(src + c * 4);
                uint2 p;
                p.x = (unsigned)f2bf(v.x) | ((unsigned)f2bf(v.y) << 16);
                p.y = (unsigned)f2bf(v.z) | ((unsigned)f2bf(v.w) << 16);
                *(uint2*)((char*)A + (size_t)r * (ASTR * 2) + c * 8) = p;
            }
        }
        #pragma unroll
        for (int k = cq; k < 5; k += 4)
            *(uint2*)((char*)A + (size_t)r * (ASTR * 2) + 600 + k * 8) = make_uint2(0u, 0u);
    }
    { const int row = x[b];
      if (tid < NC / 4) ((float4*)xemb)[tid] = ((const float4*)(embs + (size_t)row * NC))[tid]; }
    __syncthreads();

    f32x4 acc[4][4];
    #pragma unroll
    for (int mt = 0; mt < 4; ++mt)
        #pragma unroll
        for (int nt = 0; nt < 4; ++nt) acc[mt][nt] = (f32x4){0.f, 0.f, 0.f, 0.f};
    int abyte[4];
    #pragma unroll
    for (int mt = 0; mt < 4; ++mt) {
        int rr = mt * 16 + l15; if (rr >= CTXL) rr = 0;
        abyte[mt] = rr * (ASTR * 2) + lhi * 16;
    }
    const ushort* wb = W1T + (size_t)(wave * 64 + l15) * KPAD + lhi * 8;
    #pragma unroll
    for (int ks = 0; ks < KPAD / 32; ++ks) {
        s16x8 af[4], bfr[4];
        #pragma unroll
        for (int mt = 0; mt < 4; ++mt)
            af[mt] = *(const s16x8*)((const char*)A + abyte[mt] + ks * 64);
        #pragma unroll
        for (int nt = 0; nt < 4; ++nt)
            bfr[nt] = *(const s16x8*)(wb + nt * 16 * KPAD + ks * 32);
        #pragma unroll
        for (int mt = 0; mt < 4; ++mt)
            #pragma unroll
            for (int nt = 0; nt < 4; ++nt)
                acc[mt][nt] = __builtin_amdgcn_mfma_f32_16x16x32_bf16(
                    af[mt], bfr[nt], acc[mt][nt], 0, 0, 0);
    }
    #pragma unroll
    for (int nt = 0; nt < 4; ++nt) {
        const float bb = b1[wave * 64 + nt * 16 + l15];
        float s = 0.0f;
        #pragma unroll
        for (int mt = 0; mt < 4; ++mt)
            #pragma unroll
            for (int q = 0; q < 4; ++q) {
                const int row = mt * 16 + lhi * 4 + q;
                const float v = fmaxf(acc[mt][nt][q] + bb, 0.0f);
                s += (row < CTXL) ? v : 0.0f;
            }
        s += __shfl_xor(s, 16);
        s += __shfl_xor(s, 32);
        if (lhi == 0) pooled[wave * 64 + nt * 16 + l15] = s * (1.0f / CTXL);
    }
    __syncthreads();
    for (int j = tid; j < NC; j += NT) {
        float s = b2[j];
        const s16x8* wrow = (const s16x8*)(W2T + (size_t)j * NH);
        #pragma unroll 8
        for (int c = 0; c < NH / 8; ++c) {
            const s16x8 w8 = wrow[c];
            const float4 p0 = *(const float4*)(&pooled[c * 8]);
            const float4 p1 = *(const float4*)(&pooled[c * 8 + 4]);
            s = fmaf(p0.x, bf2f((ushort)w8[0]), s);
            s = fmaf(p0.y, bf2f((ushort)w8[1]), s);
            s = fmaf(p0.z, bf2f((ushort)w8[2]), s);
            s = fmaf(p0.w, bf2f((ushort)w8[3]), s);
            s = fmaf(p1.x, bf2f((ushort)w8[4]), s);
            s = fmaf(p1.y, bf2f((ushort)w8[5]), s);
            s = fmaf(p1.z, bf2f((ushort)w8[6]), s);
            s = fmaf(p1.w, bf2f((ushort)w8[7]), s);
        }
        const float g = 1.0f / (1.0f + __expf(-s));
        out[(size_t)b * NC + j] = g * xemb[j];
    }
}

extern "C" void kernel_launch(void* const* d_in, const int* in_sizes, int n_in,
                              void* d_out, int out_size, void* d_ws, size_t ws_size,
                              hipStream_t stream) {
    const int*   x    = (const int*)d_in[0];
    const int*   ctx  = (const int*)d_in[1];
    const float* embs = (const float*)d_in[2];
    const float* W1   = (const float*)d_in[3];
    const float* b1   = (const float*)d_in[4];
    const float* W2   = (const float*)d_in[5];
    const float* b2   = (const float*)d_in[6];
    float* out = (float*)d_out;

    const int B    = in_sizes[0];
    const int ntok = in_sizes[2] / NC;

    const size_t h_bytes   = (size_t)ntok * NH * 2;   // 51.2 MB
    const size_t w1t_bytes = (size_t)NH * KPAD * 2;   // 160 KB
    const size_t w2t_bytes = (size_t)NC * NH * 2;     // 150 KB

    if (ws_size >= h_bytes + w1t_bytes + w2t_bytes && (B & 3) == 0) {
        ushort* H   = (ushort*)d_ws;
        ushort* W1T = (ushort*)((char*)d_ws + h_bytes);
        ushort* W2T = (ushort*)((char*)d_ws + h_bytes + w1t_bytes);
        convert_w<<<KPAD + NC, NT, 0, stream>>>(W1, W2, W1T, W2T);
        const int ntiles = (ntok + MR - 1) / MR;
        const int k1grid = (ntiles < 512) ? ntiles : 512;   // 2 blocks/CU co-resident
        k1_hidden<<<k1grid, NT, 0, stream>>>(embs, b1, W1T, H, ntok, ntiles);
        k2_pool<<<B / 4, NT, 0, stream>>>(x, ctx, embs, H, W2T, b2, out);
    } else {
        ushort* W1T = (ushort*)d_ws;
        ushort* W2T = (ushort*)((char*)d_ws + w1t_bytes);
        convert_w<<<KPAD + NC, NT, 0, stream>>>(W1, W2, W1T, W2T);
        esa_fallback<<<B, NT, 0, stream>>>(x, ctx, embs, b1, b2, W1T, W2T, out);
    }
}